// Round 5
// baseline (118.195 us; speedup 1.0000x reference)
//
#include <hip/hip_runtime.h>

#define S      4096
#define CIN    7
#define DM     512
#define KERN   73
#define TT     128
#define TILES  (S / TT)        // 32
#define NSTAGE (TT + 17)       // 145 valid staged elements per channel row
#define TROW   148             // row stride (16B aligned; covers float4 overreads)
#define PH     8               // t per phase
#define NPH    (TT / PH)       // 16
#define SLOTF  (PH * DM)       // 4096 floats per ring slot (16 KB)

__global__ __launch_bounds__(512, 2)
void tokemb_kernel(const float* __restrict__ x,
                   const float* __restrict__ w_conv,
                   const float* __restrict__ b_conv,
                   const float* __restrict__ w_left,
                   const float* __restrict__ b_left,
                   float* __restrict__ out)
{
    __shared__ float xs[CIN * TROW];
    __shared__ float ring[2 * SLOTF];

    const int blk  = blockIdx.x;
    const int b    = blk >> 5;          // TILES = 32
    const int tile = blk & 31;
    const int t0   = tile * TT;
    const int tid  = threadIdx.x;

    // ---- stage x tile into LDS transposed: xs[c][j] = x[b, (t0-16+j) mod S, c]
    const float* xb = x + (long long)b * S * CIN;
    for (int e = tid; e < CIN * NSTAGE; e += 512) {
        int j = e / CIN, c = e - j * CIN;
        int tm = t0 - 16 + j;
        if (tm < 0) tm += S; else if (tm >= S) tm -= S;
        xs[c * TROW + j] = xb[tm * CIN + c];
    }

    const bool is_store = (tid >= 256);   // waves 4..7 = pure store streamers

    // ---- compute-role setup: thread owns d-pair (2*tid, 2*tid+1) ----
    float g[2][18], bias[2];
    const float* xr[2];
    if (!is_store) {
        const int d0 = 2 * tid;
        #pragma unroll
        for (int dd = 0; dd < 2; ++dd) {
            const int d  = d0 + dd;
            const int oo = d % KERN;
            const float* wrow = (d < DM - 1) ? (w_conv + oo * 18) : w_left;
            bias[dd] = (d < DM - 1) ? b_conv[oo] : b_left[0];
            const int cc = (d < DM - 1) ? (d / KERN) : (CIN - 1);
            xr[dd] = xs + cc * TROW;
            // FIR tap order: off = 15-3m+k -> g[off] = wrow[(5-off/3)*3 + off%3]
            #pragma unroll
            for (int off = 0; off < 18; ++off)
                g[dd][off] = wrow[(5 - off / 3) * 3 + (off % 3)];
        }
    }

    const int sid = tid - 256;            // 0..255 for store role
    float* const outb = out + ((long long)b * S + t0) * DM;

    // ring pipeline: phase p: compute fills slot p&1; store drains slot (p-1)&1
    for (int p = 0; p <= NPH; ++p) {
        __syncthreads();                  // uniform barrier, 17 per block

        if (!is_store) {
            if (p < NPH) {
                const int jb = p * PH;    // window base in xs row
                const int tc = t0 + jb;
                float* slot = ring + (p & 1) * SLOTF;
                const bool edge = (tc < 16) || (tc + PH >= S);  // block-uniform

                float acc[2][PH];
                #pragma unroll
                for (int dd = 0; dd < 2; ++dd) {
                    const float* xw = xr[dd] + jb;
                    float w4[28];
                    #pragma unroll
                    for (int q = 0; q < 7; ++q) {
                        float4 v = *reinterpret_cast<const float4*>(xw + 4 * q);
                        w4[4*q+0] = v.x; w4[4*q+1] = v.y;
                        w4[4*q+2] = v.z; w4[4*q+3] = v.w;
                    }
                    if (!edge) {
                        #pragma unroll
                        for (int i = 0; i < PH; ++i) {
                            float a = bias[dd];
                            #pragma unroll
                            for (int off = 0; off < 18; ++off)
                                a = fmaf(g[dd][off], w4[i + off], a);
                            acc[dd][i] = a;
                        }
                    } else {
                        #pragma unroll
                        for (int i = 0; i < PH; ++i) {
                            float p0 = 0.f, p1 = 0.f, p2 = 0.f;
                            #pragma unroll
                            for (int o = 0; o < 18; o += 3) {
                                p0 = fmaf(g[dd][o],     w4[i + o],     p0);
                                p1 = fmaf(g[dd][o + 1], w4[i + o + 1], p1);
                                p2 = fmaf(g[dd][o + 2], w4[i + o + 2], p2);
                            }
                            const int t = tc + i;
                            const float f0 = (t == 0 || t >= 16)     ? 1.f : 0.f;
                            const float f1 = (t >= 15)               ? 1.f : 0.f;
                            const float f2 = (t >= 14 && t != S - 1) ? 1.f : 0.f;
                            acc[dd][i] = bias[dd] + f0 * p0 + f1 * p1 + f2 * p2;
                        }
                    }
                }
                // write slot: [t_local][d], float2 per (t, d-pair)
                #pragma unroll
                for (int i = 0; i < PH; ++i) {
                    float2 v = make_float2(acc[0][i], acc[1][i]);
                    *reinterpret_cast<float2*>(slot + i * DM + 2 * tid) = v;
                }
            }
        } else {
            if (p >= 1) {
                const float4* src = reinterpret_cast<const float4*>(
                                        ring + ((p - 1) & 1) * SLOTF);
                float4* dst = reinterpret_cast<float4*>(
                                  outb + (long long)(p - 1) * PH * DM);
                #pragma unroll
                for (int r = 0; r < 4; ++r)       // 4 x 256 thr x 16 B = 16 KB
                    dst[r * 256 + sid] = src[r * 256 + sid];
            }
        }
    }
}

extern "C" void kernel_launch(void* const* d_in, const int* in_sizes, int n_in,
                              void* d_out, int out_size, void* d_ws, size_t ws_size,
                              hipStream_t stream) {
    const float* x      = (const float*)d_in[0];
    const float* w_conv = (const float*)d_in[1];
    const float* b_conv = (const float*)d_in[2];
    const float* w_left = (const float*)d_in[3];
    const float* b_left = (const float*)d_in[4];
    float* out = (float*)d_out;

    const int B = in_sizes[0] / (S * CIN);   // 32
    dim3 grid(B * TILES);
    tokemb_kernel<<<grid, 512, 0, stream>>>(x, w_conv, b_conv, w_left, b_left, out);
}

// Round 7
// 49.398 us; speedup vs baseline: 2.3927x; 2.3927x over previous
//
#include <hip/hip_runtime.h>

#define S      4096
#define CIN    7
#define DM     512
#define KERN   73
#define TT     256
#define TILES  (S / TT)        // 16
#define NSTAGE (TT + 17)       // 273 valid staged elements per channel row
#define TROW   276             // row stride (16B aligned; covers float4 overreads)
#define CHUNK  16
#define NCH    (TT / CHUNK)    // 16

// Interior chunk: 18-tap FIR on 16 consecutive t. 9x ds_read_b128, store-ASAP.
__device__ __forceinline__ void do_chunk16(const float* __restrict__ xc,
                                           const float g[18], float bias,
                                           float* __restrict__ opc)
{
    float acc[CHUNK];
    #pragma unroll
    for (int i = 0; i < CHUNK; ++i) acc[i] = bias;

    #pragma unroll
    for (int q = 0; q < 9; ++q) {
        float4 v = *reinterpret_cast<const float4*>(xc + 4 * q);
        float va[4] = {v.x, v.y, v.z, v.w};
        #pragma unroll
        for (int e = 0; e < 4; ++e) {
            const int j = 4 * q + e;
            #pragma unroll
            for (int i = 0; i < CHUNK; ++i) {
                const int off = j - i;
                if (off >= 0 && off < 18)
                    acc[i] = fmaf(g[off], va[e], acc[i]);
            }
        }
        // store outputs whose last tap (j = i + 17) just landed
        if (q == 4) {
            #pragma unroll
            for (int i = 0; i <= 2; ++i) opc[i * DM] = acc[i];
        }
        if (q == 5) {
            #pragma unroll
            for (int i = 3; i <= 6; ++i) opc[i * DM] = acc[i];
        }
        if (q == 6) {
            #pragma unroll
            for (int i = 7; i <= 10; ++i) opc[i * DM] = acc[i];
        }
        if (q == 7) {
            #pragma unroll
            for (int i = 11; i <= 14; ++i) opc[i * DM] = acc[i];
        }
        if (q == 8) {
            opc[15 * DM] = acc[15];
        }
    }
}

__global__ __launch_bounds__(512, 2)
void tokemb_kernel(const float* __restrict__ x,
                   const float* __restrict__ w_conv,
                   const float* __restrict__ b_conv,
                   const float* __restrict__ w_left,
                   const float* __restrict__ b_left,
                   float* __restrict__ out)
{
    __shared__ float xs[CIN * TROW];

    const int blk  = blockIdx.x;
    const int b    = blk / TILES;
    const int tile = blk & (TILES - 1);
    const int t0   = tile * TT;
    const int tid  = threadIdx.x;

    // ---- stage x tile into LDS transposed: xs[c][j] = x[b, (t0-16+j) mod S, c]
    const float* xb = x + (long long)b * S * CIN;
    for (int e = tid; e < CIN * NSTAGE; e += 512) {
        int j = e / CIN, c = e - j * CIN;
        int tm = t0 - 16 + j;
        if (tm < 0) tm += S; else if (tm >= S) tm -= S;
        xs[c * TROW + j] = xb[tm * CIN + c];
    }

    // ---- per-thread weights in FIR tap order ----
    const int d  = tid;
    const int oo = d % KERN;
    const float* wrow = (d < DM - 1) ? (w_conv + oo * 18) : w_left;
    const float bias  = (d < DM - 1) ? b_conv[oo] : b_left[0];
    const int cc = (d < DM - 1) ? (d / KERN) : (CIN - 1);
    float g[18];
    #pragma unroll
    for (int off = 0; off < 18; ++off)
        g[off] = wrow[(5 - off / 3) * 3 + (off % 3)];

    __syncthreads();

    const float* xrow = xs + cc * TROW;
    float* const op = out + ((long long)b * S + t0) * DM + d;

    // wave de-phasing: each wave walks chunks in a rotated order so waves sit
    // in different [LDS|FMA|store] phases at any instant (no barriers needed).
    const int wid = tid >> 6;
    const bool edgetile = (tile == 0) || (tile == TILES - 1);

    for (int cc_ = 0; cc_ < NCH; ++cc_) {
        const int ch  = ((cc_ + 2 * wid) & (NCH - 1));
        const int jb  = ch * CHUNK;
        const int tc  = t0 + jb;
        float* opc = op + jb * DM;

        if (!edgetile || !((tc < 16) || (tc + CHUNK >= S))) {
            do_chunk16(xrow + jb, g, bias, opc);
        } else {
            // masked scalar path (only tile 0 chunk 0 and tile 15 chunk 15)
            #pragma unroll
            for (int i = 0; i < CHUNK; ++i) {
                float p0 = 0.f, p1 = 0.f, p2 = 0.f;
                #pragma unroll
                for (int o = 0; o < 18; o += 3) {
                    p0 = fmaf(g[o],     xrow[jb + i + o],     p0);
                    p1 = fmaf(g[o + 1], xrow[jb + i + o + 1], p1);
                    p2 = fmaf(g[o + 2], xrow[jb + i + o + 2], p2);
                }
                const int t = tc + i;
                const float f0 = (t == 0 || t >= 16)     ? 1.f : 0.f;
                const float f1 = (t >= 15)               ? 1.f : 0.f;
                const float f2 = (t >= 14 && t != S - 1) ? 1.f : 0.f;
                opc[i * DM] = bias + f0 * p0 + f1 * p1 + f2 * p2;
            }
        }
    }
}

extern "C" void kernel_launch(void* const* d_in, const int* in_sizes, int n_in,
                              void* d_out, int out_size, void* d_ws, size_t ws_size,
                              hipStream_t stream) {
    const float* x      = (const float*)d_in[0];
    const float* w_conv = (const float*)d_in[1];
    const float* b_conv = (const float*)d_in[2];
    const float* w_left = (const float*)d_in[3];
    const float* b_left = (const float*)d_in[4];
    float* out = (float*)d_out;

    const int B = in_sizes[0] / (S * CIN);   // 32
    dim3 grid(B * TILES);
    tokemb_kernel<<<grid, 512, 0, stream>>>(x, w_conv, b_conv, w_left, b_left, out);
}

// Round 8
// 48.592 us; speedup vs baseline: 2.4324x; 1.0166x over previous
//
#include <hip/hip_runtime.h>

#define S      4096
#define CIN    7
#define DM     512
#define KERN   73
#define TT     256
#define TILES  (S / TT)        // 16
#define NSTAGE (TT + 17)       // 273 valid staged elements per channel row
#define TROW   292             // row stride (16B aligned; covers float4 overreads to j<292)
#define CHUNK  32
#define NCH    (TT / CHUNK)    // 8

// Interior chunk: 18-tap FIR on 32 consecutive t. 13x ds_read_b128, store-ASAP.
__device__ __forceinline__ void do_chunk32(const float* __restrict__ xc,
                                           const float g[18], float bias,
                                           float* __restrict__ opc)
{
    float acc[CHUNK];
    #pragma unroll
    for (int i = 0; i < CHUNK; ++i) acc[i] = bias;

    #pragma unroll
    for (int q = 0; q < 13; ++q) {
        float4 v = *reinterpret_cast<const float4*>(xc + 4 * q);
        float va[4] = {v.x, v.y, v.z, v.w};
        #pragma unroll
        for (int e = 0; e < 4; ++e) {
            const int j = 4 * q + e;
            #pragma unroll
            for (int i = 0; i < CHUNK; ++i) {
                const int off = j - i;
                if (off >= 0 && off < 18)
                    acc[i] = fmaf(g[off], va[e], acc[i]);
            }
        }
        // store outputs whose last tap (j = i + 17) has landed: after block q,
        // j_max = 4q+3, so outputs i <= 4q-14 are final.
        if (q >= 4 && q < 12) {
            const int lo = (q == 4) ? 0 : (4 * q - 17);
            const int hi = 4 * q - 14;
            #pragma unroll
            for (int i = 0; i < CHUNK; ++i)
                if (i >= lo && i <= hi) opc[i * DM] = acc[i];
        }
        if (q == 12) {
            #pragma unroll
            for (int i = 31; i <= 31; ++i) opc[i * DM] = acc[i];
        }
    }
}

__global__ __launch_bounds__(512, 2)
void tokemb_kernel(const float* __restrict__ x,
                   const float* __restrict__ w_conv,
                   const float* __restrict__ b_conv,
                   const float* __restrict__ w_left,
                   const float* __restrict__ b_left,
                   float* __restrict__ out)
{
    __shared__ float xs[CIN * TROW];

    const int blk  = blockIdx.x;
    const int b    = blk / TILES;
    const int tile = blk & (TILES - 1);
    const int t0   = tile * TT;
    const int tid  = threadIdx.x;

    // ---- stage x tile into LDS transposed: xs[c][j] = x[b, (t0-16+j) mod S, c]
    // Bulk: float4 over the contiguous source range [t0-16, t0-16+NSTAGE) (may
    // run past S or below 0 — fixed up by the seam pass below).
    {
        const float* xb = x + (long long)b * S * CIN;
        const long long base = (long long)(t0 - 16) * CIN;   // source offset of j=0
        const int nfl = CIN * NSTAGE;                        // 1911 floats
        // clamp bulk copy to in-range part of [base, base+nfl)
        for (int e4 = 4 * tid; e4 < nfl; e4 += 4 * 512) {
            long long src = base + e4;
            if (src >= 0 && src + 3 < (long long)S * CIN) {
                float4 v = *reinterpret_cast<const float4*>(xb + src);
                float va[4] = {v.x, v.y, v.z, v.w};
                #pragma unroll
                for (int u = 0; u < 4; ++u) {
                    int e = e4 + u;
                    int j = e / CIN, c = e - j * CIN;
                    xs[c * TROW + j] = va[u];
                }
            } else {
                #pragma unroll
                for (int u = 0; u < 4; ++u) {
                    int e = e4 + u;
                    if (e < nfl) {
                        int j = e / CIN, c = e - j * CIN;
                        int tm = t0 - 16 + j;
                        if (tm < 0) tm += S; else if (tm >= S) tm -= S;
                        xs[c * TROW + j] = xb[tm * CIN + c];
                    }
                }
            }
        }
    }

    // ---- per-thread weights in FIR tap order ----
    const int d  = tid;
    const int oo = d % KERN;
    const float* wrow = (d < DM - 1) ? (w_conv + oo * 18) : w_left;
    const float bias  = (d < DM - 1) ? b_conv[oo] : b_left[0];
    const int cc = (d < DM - 1) ? (d / KERN) : (CIN - 1);
    float g[18];
    #pragma unroll
    for (int off = 0; off < 18; ++off)
        g[off] = wrow[(5 - off / 3) * 3 + (off % 3)];

    __syncthreads();

    const float* xrow = xs + cc * TROW;
    float* const op = out + ((long long)b * S + t0) * DM + d;

    // wave de-phasing: each of the 8 waves starts at a different chunk.
    const int wid = tid >> 6;
    const bool edgetile = (tile == 0) || (tile == TILES - 1);

    for (int cc_ = 0; cc_ < NCH; ++cc_) {
        const int ch  = (cc_ + wid) & (NCH - 1);
        const int jb  = ch * CHUNK;
        const int tc  = t0 + jb;
        float* opc = op + jb * DM;

        if (!edgetile || !((tc < 16) || (tc + CHUNK >= S))) {
            do_chunk32(xrow + jb, g, bias, opc);
        } else {
            // masked scalar path (only tile 0 chunk 0 and tile 15 chunk 7)
            #pragma unroll
            for (int i = 0; i < CHUNK; ++i) {
                float p0 = 0.f, p1 = 0.f, p2 = 0.f;
                #pragma unroll
                for (int o = 0; o < 18; o += 3) {
                    p0 = fmaf(g[o],     xrow[jb + i + o],     p0);
                    p1 = fmaf(g[o + 1], xrow[jb + i + o + 1], p1);
                    p2 = fmaf(g[o + 2], xrow[jb + i + o + 2], p2);
                }
                const int t = tc + i;
                const float f0 = (t == 0 || t >= 16)     ? 1.f : 0.f;
                const float f1 = (t >= 15)               ? 1.f : 0.f;
                const float f2 = (t >= 14 && t != S - 1) ? 1.f : 0.f;
                opc[i * DM] = bias + f0 * p0 + f1 * p1 + f2 * p2;
            }
        }
    }
}

extern "C" void kernel_launch(void* const* d_in, const int* in_sizes, int n_in,
                              void* d_out, int out_size, void* d_ws, size_t ws_size,
                              hipStream_t stream) {
    const float* x      = (const float*)d_in[0];
    const float* w_conv = (const float*)d_in[1];
    const float* b_conv = (const float*)d_in[2];
    const float* w_left = (const float*)d_in[3];
    const float* b_left = (const float*)d_in[4];
    float* out = (float*)d_out;

    const int B = in_sizes[0] / (S * CIN);   // 32
    dim3 grid(B * TILES);
    tokemb_kernel<<<grid, 512, 0, stream>>>(x, w_conv, b_conv, w_left, b_left, out);
}

// Round 9
// 48.448 us; speedup vs baseline: 2.4396x; 1.0030x over previous
//
#include <hip/hip_runtime.h>

#define S      4096
#define CIN    7
#define DM     512
#define KERN   73
#define TT     256
#define TILES  (S / TT)        // 16
#define NSTAGE (TT + 17)       // 273 valid staged elements per channel row
#define TROW   292             // row stride (16B aligned; covers float4 overreads to j<292)
#define CHUNK  32
#define NCH    (TT / CHUNK)    // 8

typedef float f32x2 __attribute__((ext_vector_type(2)));

// Interior chunk: 18-tap FIR on 32 consecutive t via v_pk_fma_f32 (even/odd
// tap decomposition on aligned window pairs). 13x ds_read_b128, store-ASAP.
__device__ __forceinline__ void do_chunk32_pk(const float* __restrict__ xc,
                                              const f32x2 ge[9], const f32x2 go[9],
                                              float bias,
                                              float* __restrict__ opc)
{
    f32x2 accE[16];   // {even-tap sum of out[2p], even-tap sum of out[2p+1]} + bias
    f32x2 accO[17];   // {odd-tap sum of out[2p-1], odd-tap sum of out[2p]}
    #pragma unroll
    for (int p = 0; p < 16; ++p) { accE[p].x = bias; accE[p].y = bias; }
    #pragma unroll
    for (int p = 0; p < 17; ++p) { accO[p].x = 0.f; accO[p].y = 0.f; }

    #pragma unroll
    for (int q = 0; q < 13; ++q) {
        float4 v = *reinterpret_cast<const float4*>(xc + 4 * q);
        f32x2 wk0; wk0.x = v.x; wk0.y = v.y;   // we[2q]   (aligned pair)
        f32x2 wk1; wk1.x = v.z; wk1.y = v.w;   // we[2q+1] (aligned pair)

        #pragma unroll
        for (int h = 0; h < 2; ++h) {
            const int k = 2 * q + h;
            if (k > 24) continue;              // we[25] contributes nothing
            const f32x2 wk = h ? wk1 : wk0;

            #pragma unroll
            for (int m = 0; m < 9; ++m) {
                const int p = k - m;
                if (p >= 0 && p <= 15)
                    accE[p] = __builtin_elementwise_fma(ge[m], wk, accE[p]);
                if (p >= 0 && p <= 16)
                    accO[p] = __builtin_elementwise_fma(go[m], wk, accO[p]);
            }
            // store-ASAP: everything with final contribution we[k] is done
            {
                const int pa = k - 8;          // out[2*pa] ready
                if (pa >= 0 && pa <= 15)
                    opc[(2 * pa) * DM] = accE[pa].x + accO[pa].y;
                const int pb = k - 9;          // out[2*pb+1] ready
                if (pb >= 0 && pb <= 15)
                    opc[(2 * pb + 1) * DM] = accE[pb].y + accO[pb + 1].x;
            }
        }
    }
}

__global__ __launch_bounds__(512, 2)
void tokemb_kernel(const float* __restrict__ x,
                   const float* __restrict__ w_conv,
                   const float* __restrict__ b_conv,
                   const float* __restrict__ w_left,
                   const float* __restrict__ b_left,
                   float* __restrict__ out)
{
    __shared__ float xs[CIN * TROW];

    const int blk  = blockIdx.x;
    const int b    = blk / TILES;
    const int tile = blk & (TILES - 1);
    const int t0   = tile * TT;
    const int tid  = threadIdx.x;

    // ---- stage x tile into LDS transposed: xs[c][j] = x[b, (t0-16+j) mod S, c]
    {
        const float* xb = x + (long long)b * S * CIN;
        const long long base = (long long)(t0 - 16) * CIN;   // source offset of j=0
        const int nfl = CIN * NSTAGE;                        // 1911 floats
        for (int e4 = 4 * tid; e4 < nfl; e4 += 4 * 512) {
            long long src = base + e4;
            if (src >= 0 && src + 3 < (long long)S * CIN) {
                float4 v = *reinterpret_cast<const float4*>(xb + src);
                float va[4] = {v.x, v.y, v.z, v.w};
                #pragma unroll
                for (int u = 0; u < 4; ++u) {
                    int e = e4 + u;
                    int j = e / CIN, c = e - j * CIN;
                    xs[c * TROW + j] = va[u];
                }
            } else {
                #pragma unroll
                for (int u = 0; u < 4; ++u) {
                    int e = e4 + u;
                    if (e < nfl) {
                        int j = e / CIN, c = e - j * CIN;
                        int tm = t0 - 16 + j;
                        if (tm < 0) tm += S; else if (tm >= S) tm -= S;
                        xs[c * TROW + j] = xb[tm * CIN + c];
                    }
                }
            }
        }
    }

    // ---- per-thread weights, packed splats in FIR tap order ----
    // tap off = 15 - 3m + k  ->  g[off] = wrow[(5-off/3)*3 + off%3]
    const int d  = tid;
    const int oo = d % KERN;
    const float* wrow = (d < DM - 1) ? (w_conv + oo * 18) : w_left;
    const float bias  = (d < DM - 1) ? b_conv[oo] : b_left[0];
    const int cc = (d < DM - 1) ? (d / KERN) : (CIN - 1);
    f32x2 ge[9], go[9];
    #pragma unroll
    for (int m = 0; m < 9; ++m) {
        const int oe = 2 * m, od = 2 * m + 1;
        const float gev = wrow[(5 - oe / 3) * 3 + (oe % 3)];
        const float gov = wrow[(5 - od / 3) * 3 + (od % 3)];
        ge[m].x = gev; ge[m].y = gev;
        go[m].x = gov; go[m].y = gov;
    }

    __syncthreads();

    const float* xrow = xs + cc * TROW;
    float* const op = out + ((long long)b * S + t0) * DM + d;

    // wave de-phasing: each of the 8 waves starts at a different chunk.
    const int wid = tid >> 6;
    const bool edgetile = (tile == 0) || (tile == TILES - 1);

    for (int cc_ = 0; cc_ < NCH; ++cc_) {
        const int ch  = (cc_ + wid) & (NCH - 1);
        const int jb  = ch * CHUNK;
        const int tc  = t0 + jb;
        float* opc = op + jb * DM;

        if (!edgetile || !((tc < 16) || (tc + CHUNK >= S))) {
            do_chunk32_pk(xrow + jb, ge, go, bias, opc);
        } else {
            // masked scalar path (only tile 0 chunk 0 and tile 15 chunk 7)
            float gs[18];
            #pragma unroll
            for (int off = 0; off < 18; ++off)
                gs[off] = (off & 1) ? go[off >> 1].x : ge[off >> 1].x;
            #pragma unroll
            for (int i = 0; i < CHUNK; ++i) {
                float p0 = 0.f, p1 = 0.f, p2 = 0.f;
                #pragma unroll
                for (int o = 0; o < 18; o += 3) {
                    p0 = fmaf(gs[o],     xrow[jb + i + o],     p0);
                    p1 = fmaf(gs[o + 1], xrow[jb + i + o + 1], p1);
                    p2 = fmaf(gs[o + 2], xrow[jb + i + o + 2], p2);
                }
                const int t = tc + i;
                const float f0 = (t == 0 || t >= 16)     ? 1.f : 0.f;
                const float f1 = (t >= 15)               ? 1.f : 0.f;
                const float f2 = (t >= 14 && t != S - 1) ? 1.f : 0.f;
                opc[i * DM] = bias + f0 * p0 + f1 * p1 + f2 * p2;
            }
        }
    }
}

extern "C" void kernel_launch(void* const* d_in, const int* in_sizes, int n_in,
                              void* d_out, int out_size, void* d_ws, size_t ws_size,
                              hipStream_t stream) {
    const float* x      = (const float*)d_in[0];
    const float* w_conv = (const float*)d_in[1];
    const float* b_conv = (const float*)d_in[2];
    const float* w_left = (const float*)d_in[3];
    const float* b_left = (const float*)d_in[4];
    float* out = (float*)d_out;

    const int B = in_sizes[0] / (S * CIN);   // 32
    dim3 grid(B * TILES);
    tokemb_kernel<<<grid, 512, 0, stream>>>(x, w_conv, b_conv, w_left, b_left, out);
}